// Round 2
// baseline (617.894 us; speedup 1.0000x reference)
//
#include <hip/hip_runtime.h>
#include <cstdint>

#define ROW_N 8192
#define TPB   256
#define CAP   512

// Order-preserving float->uint32 transform: unsigned compare == float compare.
__device__ __forceinline__ unsigned int fkey(float p) {
  unsigned int b = __float_as_uint(p);
  return (b & 0x80000000u) ? ~b : (b | 0x80000000u);
}
__device__ __forceinline__ float fkey_inv(unsigned int t) {
  unsigned int b = (t & 0x80000000u) ? (t & 0x7fffffffu) : ~t;
  return __uint_as_float(b);
}

// Approximate screening key: key2 = perturbed * log2e, via 2 native v_log_f32.
// w = -ln(u+eps)+eps computed in log2 domain; monotone transform of the precise
// perturbed value. For w < 1e-5 (u extremely close to 1 -> huge gumbel, and the
// region where HW log2's abs error near 1.0 becomes a large *relative* error on
// w) we force candidacy with a saturated key; the precise recompute ranks them.
__device__ __forceinline__ unsigned int akey(float lg, float uu) {
  float l2u = __log2f(uu + 1e-8f);
  float w   = fmaf(l2u, -0.6931471805599453f, 1e-8f);
  float p2  = fmaf(lg, 1.4426950408889634f, -__log2f(w));
  p2 = (w < 1e-5f) ? 3.0e38f : p2;
  return fkey(p2);
}

__device__ __forceinline__ uint64_t shfl_xor_u64(uint64_t v, int m) {
  unsigned int lo = (unsigned int)v, hi = (unsigned int)(v >> 32);
  lo = __shfl_xor(lo, m, 64);
  hi = __shfl_xor(hi, m, 64);
  return ((uint64_t)hi << 32) | lo;
}
__device__ __forceinline__ uint64_t wave_max_u64(uint64_t v) {
#pragma unroll
  for (int s = 32; s >= 1; s >>= 1) {
    uint64_t o = shfl_xor_u64(v, s);
    v = (o > v) ? o : v;
  }
  return v;
}

struct alignas(16) u64x2 { uint64_t a, b; };

typedef const __attribute__((address_space(1))) unsigned int* gas_u32;
typedef __attribute__((address_space(3)))       unsigned int* las_u32;

// Async global->LDS, 16 B per lane, zero VGPR payload cost. LDS dest is
// wave-uniform base + lane*16 (linear); our source is lane-consecutive 16 B,
// so layout is exactly linear (both-sides-linear rule, m104).
#define STAGE16(gp, lp) \
  __builtin_amdgcn_global_load_lds((gas_u32)(gp), (las_u32)(lp), 16, 0, 0)

// Consume chunk c after its two stage ops (issue order L0,U0,L1,U1,...) have
// retired: counted wait vmcnt(14-2c) over the 16 issued stages — never drains
// the younger stages (T4 idiom). "memory" clobber + sched_barrier(0) pin the
// dependent ds_reads after the wait (guide rule #18).
#define CONSUME(c, N)                                                          \
  {                                                                            \
    asm volatile("s_waitcnt vmcnt(" #N ")" ::: "memory");                      \
    __builtin_amdgcn_sched_barrier(0);                                         \
    float4 lv = *reinterpret_cast<const float4*>(&s_L[wbase + (c)*256 + loff]);\
    float4 uv = *reinterpret_cast<const float4*>(&s_U[wbase + (c)*256 + loff]);\
    k[(c)*4 + 0] = akey(lv.x, uv.x);                                           \
    k[(c)*4 + 1] = akey(lv.y, uv.y);                                           \
    k[(c)*4 + 2] = akey(lv.z, uv.z);                                           \
    k[(c)*4 + 3] = akey(lv.w, uv.w);                                           \
    M = max(M, max(max(k[(c)*4+0], k[(c)*4+1]), max(k[(c)*4+2], k[(c)*4+3]))); \
  }

// LDS 64 KB staging caps us at 2 blocks/CU; VGPRs are no longer the MLP lever,
// so give regalloc freedom (cap 256).
__global__ __launch_bounds__(TPB, 2) void gumbel_topk_kernel(
    const float* __restrict__ logits, const float* __restrict__ u,
    float* __restrict__ out) {
  const int row  = blockIdx.x;
  const int tid  = threadIdx.x;
  const int lane = tid & 63;
  const int wave = tid >> 6;

  // 64 KB staging: s_L = [0..8191], s_U = [8192..16383]. After D1a the first
  // 6.2 KB are overlaid by s_comp (CAP+2 u64) + s_lg (CAP floats).
  __shared__ alignas(16) float s_stage[2 * ROW_N];
  __shared__ unsigned int s_idx[CAP];                 // candidate element indices
  __shared__ alignas(16) unsigned int s_gmax[64];     // group-of-4 thread maxes
  __shared__ unsigned int s_cnt, s_t;
  __shared__ float s_red[8];                          // [0..3] wave maxes, [4..7] wave sums

  float* s_L = s_stage;
  float* s_U = s_stage + ROW_N;

  if (tid == 0) { s_cnt = 0; s_t = 0xFFFFFFFFu; }

  const float* Lrow = logits + (size_t)row * ROW_N;
  const float* Urow = u      + (size_t)row * ROW_N;
  float4*      O4   = reinterpret_cast<float4*>(out) + (size_t)row * (ROW_N / 4);

  // Wave w owns row elements [w*2048, (w+1)*2048): fully wave-private staging,
  // NO barriers anywhere in phase A.
  const int wbase = wave * 2048;
  const int loff  = lane * 4;

  // ---- Phase A-issue: 16 x 1 KB async stages per wave, all outstanding at once.
#pragma unroll
  for (int i = 0; i < 8; ++i) {
    STAGE16(Lrow + wbase + i * 256 + loff, &s_L[wbase + i * 256]);
    STAGE16(Urow + wbase + i * 256 + loff, &s_U[wbase + i * 256]);
  }

  // ---- Phase A-consume: counted vmcnt ladder; 2 v_log + 3 fma per element.
  unsigned int k[32];
  unsigned int M = 0;
  CONSUME(0, 14) CONSUME(1, 12) CONSUME(2, 10) CONSUME(3, 8)
  CONSUME(4, 6)  CONSUME(5, 4)  CONSUME(6, 2)  CONSUME(7, 0)

  // ---- Zero-fill output row (issued after all stages retired; overlaps the
  // selection phases below; barriers before the final scatter order them).
  {
    float4 z = make_float4(0.f, 0.f, 0.f, 0.f);
#pragma unroll
    for (int j = 0; j < 8; ++j) O4[j * TPB + tid] = z;
  }

  // ---- Phase B: t = 32nd-largest of 64 group-of-4-thread maxes (each group
  // max IS a distinct element => t <= true 32nd-largest element key).
  {
    unsigned int g = max(M, (unsigned int)__shfl_xor(M, 1, 64));
    g = max(g, (unsigned int)__shfl_xor(g, 2, 64));
    if ((tid & 3) == 0) s_gmax[tid >> 2] = g;
  }
  __syncthreads();
  if (tid < 64) {
    unsigned int mine = s_gmax[tid];
    unsigned int cnt = 0;
    const uint4* gm4 = reinterpret_cast<const uint4*>(s_gmax);
#pragma unroll
    for (int i = 0; i < 16; ++i) {
      uint4 v = gm4[i];
      cnt += (v.x > mine) + (v.y > mine) + (v.z > mine) + (v.w > mine);
    }
    if (cnt < 32) atomicMin(&s_t, mine);  // min over top-32 group maxes
  }
  __syncthreads();
  // Screening threshold with margin Delta = 0.25 log2-units (>= 2x approx error).
  const unsigned int tm = fkey(fkey_inv(s_t) - 0.25f);

  // ---- Phase C: collect candidate indices (approx key >= tm). Element index
  // for k[j*4+c] under the wave-private layout: wbase + j*256 + lane*4 + c.
  const unsigned int tbase = (unsigned int)(wbase + loff);
#pragma unroll
  for (int j = 0; j < 8; ++j) {
#pragma unroll
    for (int c = 0; c < 4; ++c) {
      if (k[j * 4 + c] >= tm) {
        unsigned int slot = atomicAdd(&s_cnt, 1u);
        if (slot < CAP)
          s_idx[slot] = tbase + (unsigned int)(j * 256 + c);
      }
    }
  }
  __syncthreads();
  unsigned int C = s_cnt;

  // ---- Fallback (adversarial ties only; never taken for iid data): exact
  // per-wave top-32 by approx composite -> union of 128 indices.
  if (C > CAP) {
#pragma unroll 1
    for (int it = 0; it < 32; ++it) {
      uint64_t lm = 0;
#pragma unroll
      for (int i = 0; i < 32; ++i) {
        unsigned int idx = tbase + (unsigned int)((i >> 2) * 256 + (i & 3));
        uint64_t comp = ((uint64_t)k[i] << 13) | (uint64_t)(8191u - idx);
        if (k[i] != 0u && comp > lm) lm = comp;
      }
      uint64_t wm = wave_max_u64(lm);
      if (lm == wm) {
#pragma unroll
        for (int i = 0; i < 32; ++i) {
          unsigned int idx = tbase + (unsigned int)((i >> 2) * 256 + (i & 3));
          uint64_t comp = ((uint64_t)k[i] << 13) | (uint64_t)(8191u - idx);
          if (comp == wm) k[i] = 0u;
        }
      }
      if (lane == 0) s_idx[wave * 32 + it] = 8191u - (unsigned int)(wm & 8191u);
    }
    __syncthreads();
    C = 128;
  }

  // ---- Phase D1a: precise recompute for candidates, reading L/U from LDS
  // staging (no global gather). Values held in regs until staging reads done.
  uint64_t compv[2];
  float    lgvv[2];
  unsigned int idxs[2];
#pragma unroll
  for (int s = 0; s < 2; ++s) {
    unsigned int vi = (unsigned int)tid + (unsigned int)s * TPB;
    compv[s] = 0; lgvv[s] = 0.f; idxs[s] = 0;
    if (vi < C) {
      unsigned int idx = s_idx[vi];
      idxs[s] = idx;
      float lg = s_L[idx];
      float uu = s_U[idx];
      float p  = lg - logf(-logf(uu + 1e-8f) + 1e-8f);
      compv[s] = ((uint64_t)fkey(p) << 13) | (uint64_t)(8191u - idx);
      lgvv[s]  = lg;
    }
  }
  __syncthreads();   // all staging reads complete before overlay writes

  // ---- Phase D1b: write composites into the overlay region of s_stage.
  uint64_t* s_comp = reinterpret_cast<uint64_t*>(s_stage);   // (CAP+2) u64
  float*    s_lg   = s_stage + 2 * (CAP + 2);                // CAP floats
#pragma unroll
  for (int s = 0; s < 2; ++s) {
    unsigned int vi = (unsigned int)tid + (unsigned int)s * TPB;
    if (vi < C) { s_comp[vi] = compv[s]; s_lg[vi] = lgvv[s]; }
  }
  if (tid == 0) s_comp[C] = 0;  // pad so the paired D2 reads never see garbage
  __syncthreads();

  // ---- Phase D2: exact selection by rank-counting (rank < 32 <=> selected;
  // composites distinct => exactly 32 selected). Paired b128 broadcast reads.
  float m_local = -3.4e38f;
  unsigned int sel = 0;
  float lgs[2];
  const unsigned int CP = (C + 1u) >> 1;   // pairs (pad covers odd C)
#pragma unroll
  for (int s = 0; s < 2; ++s) {
    unsigned int vi = (unsigned int)tid + (unsigned int)s * TPB;
    lgs[s] = 0.f;
    if (vi < C) {
      uint64_t mine = compv[s];
      unsigned int cnt = 0;
      const u64x2* c2 = reinterpret_cast<const u64x2*>(s_comp);
#pragma unroll 1
      for (unsigned int i = 0; i < CP; ++i) {
        u64x2 v = c2[i];
        cnt += (v.a > mine) ? 1u : 0u;
        cnt += (v.b > mine) ? 1u : 0u;
      }
      if (cnt < 32) {
        sel |= (1u << s);
        lgs[s] = lgvv[s];
        m_local = fmaxf(m_local, lgs[s]);
      }
    }
  }

  // Block-wide max of selected logits.
  float m = m_local;
#pragma unroll
  for (int s = 32; s >= 1; s >>= 1) m = fmaxf(m, __shfl_xor(m, s, 64));
  if (lane == 0) s_red[wave] = m;
  __syncthreads();
  m = fmaxf(fmaxf(s_red[0], s_red[1]), fmaxf(s_red[2], s_red[3]));

  float e0 = (sel & 1u) ? expf(lgs[0] - m) : 0.f;
  float e1 = (sel & 2u) ? expf(lgs[1] - m) : 0.f;
  float sum = e0 + e1;
#pragma unroll
  for (int s = 32; s >= 1; s >>= 1) sum += __shfl_xor(sum, s, 64);
  if (lane == 0) s_red[4 + wave] = sum;
  __syncthreads();
  sum = (s_red[4] + s_red[5]) + (s_red[6] + s_red[7]);

  // Scatter the 32 softmax weights (ordered after the zero-fill by the barriers).
  float* Orow = out + (size_t)row * ROW_N;
  if (sel & 1u) Orow[idxs[0]] = e0 / sum;
  if (sel & 2u) Orow[idxs[1]] = e1 / sum;
}

extern "C" void kernel_launch(void* const* d_in, const int* in_sizes, int n_in,
                              void* d_out, int out_size, void* d_ws, size_t ws_size,
                              hipStream_t stream) {
  const float* logits = (const float*)d_in[0];
  const float* u      = (const float*)d_in[1];
  float*       out    = (float*)d_out;
  int rows = in_sizes[0] / ROW_N;   // 8192
  gumbel_topk_kernel<<<dim3(rows), dim3(TPB), 0, stream>>>(logits, u, out);
}